// Round 1
// baseline (1584.647 us; speedup 1.0000x reference)
//
#include <hip/hip_runtime.h>
#include <math.h>

typedef unsigned short u16;
typedef unsigned int   u32;
typedef __attribute__((ext_vector_type(8))) short short8;
typedef __attribute__((ext_vector_type(4))) float f32x4;

#define H_   16
#define B_   2
#define L_   2048
#define C_   2048
#define D_   128
#define CM_  8192
#define SIXC_ (6*C_)
#define M_   (B_*L_)

__device__ __forceinline__ u16 f2bf(float f) {
  u32 u = __float_as_uint(f);
  u = (u + 0x7fffu + ((u >> 16) & 1u)) >> 16;
  return (u16)u;
}

// ---------------- weight transpose+cast: W f32 [K][N] -> Wt bf16 [N][K] ----
__global__ __launch_bounds__(256)
void wt_transpose(const float* __restrict__ Wf, u16* __restrict__ Wt, int K, int N)
{
  __shared__ float tile[32][33];
  const int n0 = blockIdx.x * 32, k0 = blockIdx.y * 32;
  const int t = threadIdx.x;
  const int r = t >> 5, c = t & 31;
  #pragma unroll
  for (int i = 0; i < 4; i++)
    tile[i*8 + r][c] = Wf[(long)(k0 + i*8 + r)*N + n0 + c];
  __syncthreads();
  #pragma unroll
  for (int i = 0; i < 4; i++)
    Wt[(long)(n0 + i*8 + r)*K + k0 + c] = f2bf(tile[c][i*8 + r]);
}

// ---------------- V transpose: vf f32 [B][L][H][D] -> vt bf16 [B][H][D][L] --
__global__ __launch_bounds__(256)
void v_transpose(const float* __restrict__ vf, u16* __restrict__ vt)
{
  __shared__ float tile[32][33];
  const int l0 = blockIdx.x * 32, d0 = blockIdx.y * 32;
  const int bh = blockIdx.z;
  const int b = bh >> 4, h = bh & 15;
  const int t = threadIdx.x;
  const int r = t >> 5, c = t & 31;
  #pragma unroll
  for (int i = 0; i < 4; i++)
    tile[i*8 + r][c] = vf[(((long)b*L_ + l0 + i*8 + r)*H_ + h)*D_ + d0 + c];
  __syncthreads();
  #pragma unroll
  for (int i = 0; i < 4; i++)
    vt[((long)bh*D_ + d0 + i*8 + r)*L_ + l0 + c] = f2bf(tile[c][i*8 + r]);
}

// ---------------- mod = silu(vec) @ mod_w + mod_b --------------------------
__global__ __launch_bounds__(256)
void mod_init(const float* __restrict__ mb, float* __restrict__ mod)
{
  int i = blockIdx.x * 256 + threadIdx.x;           // 0 .. B*6C-1
  mod[i] = mb[i % SIXC_];
}

__global__ __launch_bounds__(256)
void mod_accum(const float* __restrict__ vec, const float* __restrict__ mw,
               float* __restrict__ mod)
{
  const int j  = blockIdx.x * 256 + threadIdx.x;    // 0..6C-1
  const int c0 = blockIdx.y * 128;
  const int b  = blockIdx.z;
  float s = 0.f;
  for (int c = c0; c < c0 + 128; c++) {
    float v  = vec[b*C_ + c];
    float sv = v / (1.0f + expf(-v));
    s += sv * mw[(long)c*SIXC_ + j];
  }
  atomicAdd(&mod[b*SIXC_ + j], s);
}

// ---------------- LayerNorm + modulate -> bf16 -----------------------------
__global__ __launch_bounds__(256)
void ln_mod(const float* __restrict__ x, const float* __restrict__ mod,
            u16* __restrict__ out, int sh_off, int sc_off)
{
  const int row = blockIdx.x;          // 0..M-1
  const int b   = row >> 11;           // row / L
  const int t   = threadIdx.x;
  const int l   = t & 63, w = t >> 6;
  const float* xr = x + (long)row * C_;
  float4 v0 = *(const float4*)(xr + t*8);
  float4 v1 = *(const float4*)(xr + t*8 + 4);
  float xs[8] = {v0.x, v0.y, v0.z, v0.w, v1.x, v1.y, v1.z, v1.w};
  float s = 0.f;
  #pragma unroll
  for (int i = 0; i < 8; i++) s += xs[i];
  #pragma unroll
  for (int o = 1; o < 64; o <<= 1) s += __shfl_xor(s, o, 64);
  __shared__ float r1[4], r2[4];
  if (l == 0) r1[w] = s;
  __syncthreads();
  float mu = (r1[0] + r1[1] + r1[2] + r1[3]) * (1.0f / C_);
  float vs = 0.f;
  #pragma unroll
  for (int i = 0; i < 8; i++) { float d = xs[i] - mu; vs += d*d; }
  #pragma unroll
  for (int o = 1; o < 64; o <<= 1) vs += __shfl_xor(vs, o, 64);
  if (l == 0) r2[w] = vs;
  __syncthreads();
  float var  = (r2[0] + r2[1] + r2[2] + r2[3]) * (1.0f / C_);
  float rstd = rsqrtf(var + 1e-6f);
  const float* shp = mod + b*SIXC_ + sh_off;
  const float* scp = mod + b*SIXC_ + sc_off;
  u16 o8[8];
  #pragma unroll
  for (int i = 0; i < 8; i++) {
    int col = t*8 + i;
    o8[i] = f2bf((xs[i] - mu)*rstd*(1.0f + scp[col]) + shp[col]);
  }
  *(short8*)(out + (long)row*C_ + t*8) = *(short8*)o8;
}

// ---------------- per-head RMSNorm (D=128) f32 -> bf16 ---------------------
__global__ __launch_bounds__(256)
void rms_cast(const float* __restrict__ in, const float* __restrict__ w,
              u16* __restrict__ out)
{
  const int row = blockIdx.x;
  const int t   = threadIdx.x;
  const long base = (long)row*C_ + t*8;
  float4 v0 = *(const float4*)(in + base);
  float4 v1 = *(const float4*)(in + base + 4);
  float xs[8] = {v0.x, v0.y, v0.z, v0.w, v1.x, v1.y, v1.z, v1.w};
  float ss = 0.f;
  #pragma unroll
  for (int i = 0; i < 8; i++) ss += xs[i]*xs[i];
  #pragma unroll
  for (int o = 1; o < 16; o <<= 1) ss += __shfl_xor(ss, o, 64);
  float sc = rsqrtf(ss * (1.0f/D_) + 1e-6f);
  const int d0 = (t & 15) * 8;
  u16 o8[8];
  #pragma unroll
  for (int i = 0; i < 8; i++) o8[i] = f2bf(xs[i]*sc*w[d0 + i]);
  *(short8*)(out + base) = *(short8*)o8;
}

// ---------------- GEMM: A[M,K] bf16 x Bt[N,K] bf16 -> C[M,N] ---------------
// MODE 0: C f32 = acc
// MODE 1: C bf16 = gelu_tanh(acc + bias[n])
// MODE 2: C f32 = resid + mod[b,goff+n]*acc
// MODE 3: C f32 = resid + mod[b,goff+n]*(acc + bias[n])
template<int MODE>
__global__ __launch_bounds__(256)
void gemm_bt(const u16* __restrict__ A, const u16* __restrict__ Bt,
             int N, int K,
             float* __restrict__ Cf, u16* __restrict__ Cb,
             const float* __restrict__ bias,
             const float* __restrict__ resid,
             const float* __restrict__ mod, int goff)
{
  __shared__ __attribute__((aligned(16))) u16 As[128*32];
  __shared__ __attribute__((aligned(16))) u16 Bs[128*32];
  const int tid = threadIdx.x;
  const int l   = tid & 63;
  const int llo = l & 15, lhi = l >> 4;
  const int w   = tid >> 6;
  const int m0 = blockIdx.y * 128, n0 = blockIdx.x * 128;
  const int wm = (w >> 1) * 64, wn = (w & 1) * 64;

  const u16* Ag = A  + (long)m0 * K;
  const u16* Bg = Bt + (long)n0 * K;

  f32x4 acc[4][4];
  #pragma unroll
  for (int i = 0; i < 4; i++)
    #pragma unroll
    for (int j = 0; j < 4; j++) acc[i][j] = (f32x4){0.f, 0.f, 0.f, 0.f};

  for (int k0 = 0; k0 < K; k0 += 32) {
    __syncthreads();
    #pragma unroll
    for (int cc = tid; cc < 512; cc += 256) {
      int row = cc >> 2, kc = (cc & 3) << 3;
      *(short8*)&As[cc*8] = *(const short8*)(Ag + (long)row*K + k0 + kc);
      *(short8*)&Bs[cc*8] = *(const short8*)(Bg + (long)row*K + k0 + kc);
    }
    __syncthreads();
    short8 a[4], b[4];
    #pragma unroll
    for (int f = 0; f < 4; f++) {
      a[f] = *(const short8*)&As[(wm + f*16 + llo)*32 + lhi*8];
      b[f] = *(const short8*)&Bs[(wn + f*16 + llo)*32 + lhi*8];
    }
    #pragma unroll
    for (int mf = 0; mf < 4; mf++)
      #pragma unroll
      for (int nf = 0; nf < 4; nf++)
        acc[mf][nf] = __builtin_amdgcn_mfma_f32_16x16x32_bf16(a[mf], b[nf], acc[mf][nf], 0, 0, 0);
  }

  #pragma unroll
  for (int mf = 0; mf < 4; mf++) {
    #pragma unroll
    for (int j = 0; j < 4; j++) {
      const int  r  = m0 + wm + mf*16 + lhi*4 + j;
      const long rb = (long)r * N;
      const int  bb = r >> 11;               // row / L (only valid when N==C_)
      #pragma unroll
      for (int nf = 0; nf < 4; nf++) {
        const int col = n0 + wn + nf*16 + llo;
        float x = acc[mf][nf][j];
        if (MODE == 0) {
          Cf[rb + col] = x;
        } else if (MODE == 1) {
          x += bias[col];
          float g = 0.5f*x*(1.0f + tanhf(0.7978845608028654f*(x + 0.044715f*x*x*x)));
          Cb[rb + col] = f2bf(g);
        } else if (MODE == 2) {
          Cf[rb + col] = resid[rb + col] + mod[bb*SIXC_ + goff + col] * x;
        } else {
          Cf[rb + col] = resid[rb + col] + mod[bb*SIXC_ + goff + col] * (x + bias[col]);
        }
      }
    }
  }
}

// ---------------- causal flash attention -----------------------------------
// qb,kb: [B][L][H][D] bf16 ; vt: [B][H][D][L] bf16 ; out: [B][L][C] bf16
// one wave per (b, h, 16 q-rows); KV tiles of 32; swapped QK^T (mfma(K,Q))
__global__ __launch_bounds__(64)
void attn(const u16* __restrict__ qb, const u16* __restrict__ kb,
          const u16* __restrict__ vt, u16* __restrict__ out)
{
  const int qt = blockIdx.x, bh = blockIdx.y;
  const int b = bh >> 4, h = bh & 15;
  const int l = threadIdx.x;
  const int llo = l & 15, lhi = l >> 4;
  const int q0 = qt * 16;

  __shared__ __attribute__((aligned(16))) u16 Plds[16*32];

  short8 qf[4];
  const u16* qrow = qb + (((long)b*L_ + q0 + llo)*H_ + h)*D_;
  #pragma unroll
  for (int dc = 0; dc < 4; dc++) qf[dc] = *(const short8*)(qrow + dc*32 + lhi*8);

  f32x4 o[8];
  #pragma unroll
  for (int f = 0; f < 8; f++) o[f] = (f32x4){0.f, 0.f, 0.f, 0.f};
  float mreg = -1e30f, lsum = 0.f;

  const int ntiles = (q0 + 16 + 31) >> 5;
  const u16* kbase = kb + ((long)b*L_*H_ + h)*D_;
  const u16* vbase = vt + (long)bh*D_*L_;
  const float scale = 0.08838834764831845f;   // 1/sqrt(128)

  for (int kt = 0; kt < ntiles; kt++) {
    const int kv0 = kt * 32;
    f32x4 st[2];
    st[0] = (f32x4){0.f,0.f,0.f,0.f};
    st[1] = (f32x4){0.f,0.f,0.f,0.f};
    #pragma unroll
    for (int mf = 0; mf < 2; mf++) {
      const u16* krow = kbase + (long)(kv0 + mf*16 + llo)*(H_*D_);
      #pragma unroll
      for (int dc = 0; dc < 4; dc++) {
        short8 kfr = *(const short8*)(krow + dc*32 + lhi*8);
        st[mf] = __builtin_amdgcn_mfma_f32_16x16x32_bf16(kfr, qf[dc], st[mf], 0, 0, 0);
      }
    }
    const int qcol = q0 + llo;
    float sv[8];
    float tmax = -1e30f;
    #pragma unroll
    for (int mf = 0; mf < 2; mf++)
      #pragma unroll
      for (int j = 0; j < 4; j++) {
        int key = kv0 + mf*16 + lhi*4 + j;
        float x = st[mf][j] * scale;
        x = (key > qcol) ? -1e30f : x;
        sv[mf*4 + j] = x;
        tmax = fmaxf(tmax, x);
      }
    tmax = fmaxf(tmax, __shfl_xor(tmax, 16, 64));
    tmax = fmaxf(tmax, __shfl_xor(tmax, 32, 64));
    float mnew  = fmaxf(mreg, tmax);
    float alpha = __expf(mreg - mnew);
    float psum = 0.f;
    u16 pb[8];
    #pragma unroll
    for (int i = 0; i < 8; i++) {
      float p = __expf(sv[i] - mnew);
      psum += p;
      pb[i] = f2bf(p);
    }
    psum += __shfl_xor(psum, 16, 64);
    psum += __shfl_xor(psum, 32, 64);
    lsum = lsum*alpha + psum;
    mreg = mnew;
    #pragma unroll
    for (int j = 0; j < 4; j++) {
      float aj = __shfl(alpha, lhi*4 + j, 64);
      #pragma unroll
      for (int f = 0; f < 8; f++) o[f][j] *= aj;
    }
    // P^T -> LDS as P[q][key_rel] (16x32 bf16), packed pairs
    #pragma unroll
    for (int mf = 0; mf < 2; mf++) {
      u32 w0 = (u32)pb[mf*4+0] | ((u32)pb[mf*4+1] << 16);
      u32 w1 = (u32)pb[mf*4+2] | ((u32)pb[mf*4+3] << 16);
      *(u32*)&Plds[llo*32 + mf*16 + lhi*4]     = w0;
      *(u32*)&Plds[llo*32 + mf*16 + lhi*4 + 2] = w1;
    }
    __syncthreads();
    short8 pf = *(const short8*)&Plds[llo*32 + lhi*8];
    #pragma unroll
    for (int f = 0; f < 8; f++) {
      short8 vfr = *(const short8*)(vbase + (long)(f*16 + llo)*L_ + kv0 + lhi*8);
      o[f] = __builtin_amdgcn_mfma_f32_16x16x32_bf16(pf, vfr, o[f], 0, 0, 0);
    }
    __syncthreads();
  }

  #pragma unroll
  for (int j = 0; j < 4; j++) {
    float lq  = __shfl(lsum, lhi*4 + j, 64);
    float inv = 1.0f / lq;
    const int qr = q0 + lhi*4 + j;
    u16* orow = out + ((long)b*L_ + qr)*C_ + h*D_;
    #pragma unroll
    for (int f = 0; f < 8; f++)
      orow[f*16 + llo] = f2bf(o[f][j] * inv);
  }
}

// ---------------------------------------------------------------------------
extern "C" void kernel_launch(void* const* d_in, const int* in_sizes, int n_in,
                              void* d_out, int out_size, void* d_ws, size_t ws_size,
                              hipStream_t stream)
{
  const float* txt    = (const float*)d_in[0];
  const float* vec    = (const float*)d_in[1];
  const float* mod_w  = (const float*)d_in[2];
  const float* mod_b  = (const float*)d_in[3];
  const float* q_w    = (const float*)d_in[4];
  const float* k_w    = (const float*)d_in[5];
  const float* v_w    = (const float*)d_in[6];
  const float* qn_w   = (const float*)d_in[7];
  const float* kn_w   = (const float*)d_in[8];
  const float* proj_w = (const float*)d_in[9];
  const float* fc1_w  = (const float*)d_in[10];
  const float* fc1_b  = (const float*)d_in[11];
  const float* fc2_w  = (const float*)d_in[12];
  const float* fc2_b  = (const float*)d_in[13];
  float* out = (float*)d_out;

  char* ws = (char*)d_ws;
  size_t off = 0;
  auto alloc = [&](size_t bytes) {
    size_t r = off; off += (bytes + 255) & ~(size_t)255; return r;
  };
  float* mod  = (float*)(ws + alloc((size_t)B_*SIXC_*4));
  u16*  qwt   = (u16*)(ws + alloc((size_t)C_*C_*2));
  u16*  kwt   = (u16*)(ws + alloc((size_t)C_*C_*2));
  u16*  vwt   = (u16*)(ws + alloc((size_t)C_*C_*2));
  u16*  pwt   = (u16*)(ws + alloc((size_t)C_*C_*2));
  u16*  f1wt  = (u16*)(ws + alloc((size_t)C_*CM_*2));
  u16*  f2wt  = (u16*)(ws + alloc((size_t)C_*CM_*2));
  u16*  xm    = (u16*)(ws + alloc((size_t)M_*C_*2));   // later reused: attn_out
  float* qf   = (float*)(ws + alloc((size_t)M_*C_*4)); // later reused: txt2
  float* kf   = (float*)(ws + alloc((size_t)M_*C_*4)); // later reused: h1 (spans kf+vf)
  float* vf   = (float*)(ws + alloc((size_t)M_*C_*4));
  u16*  qbb   = (u16*)(ws + alloc((size_t)M_*C_*2));   // later reused: x2m
  u16*  kbb   = (u16*)(ws + alloc((size_t)M_*C_*2));
  u16*  vtt   = (u16*)(ws + alloc((size_t)M_*C_*2));
  u16*   h1     = (u16*)kf;
  float* txt2   = qf;
  u16*   x2m    = qbb;
  u16*   attn_o = xm;

  // 1. weight cast+transpose (f32 [K][N] -> bf16 [N][K])
  wt_transpose<<<dim3(C_/32,  C_/32 ), 256, 0, stream>>>(q_w,    qwt,  C_,  C_);
  wt_transpose<<<dim3(C_/32,  C_/32 ), 256, 0, stream>>>(k_w,    kwt,  C_,  C_);
  wt_transpose<<<dim3(C_/32,  C_/32 ), 256, 0, stream>>>(v_w,    vwt,  C_,  C_);
  wt_transpose<<<dim3(C_/32,  C_/32 ), 256, 0, stream>>>(proj_w, pwt,  C_,  C_);
  wt_transpose<<<dim3(CM_/32, C_/32 ), 256, 0, stream>>>(fc1_w,  f1wt, C_,  CM_);
  wt_transpose<<<dim3(C_/32,  CM_/32), 256, 0, stream>>>(fc2_w,  f2wt, CM_, C_);

  // 2. modulation vector
  mod_init <<<dim3(B_*SIXC_/256), 256, 0, stream>>>(mod_b, mod);
  mod_accum<<<dim3(SIXC_/256, C_/128, B_), 256, 0, stream>>>(vec, mod_w, mod);

  // 3. LN1 + modulate
  ln_mod<<<dim3(M_), 256, 0, stream>>>(txt, mod, xm, 0, C_);

  // 4. QKV GEMMs (f32 out)
  gemm_bt<0><<<dim3(C_/128, M_/128), 256, 0, stream>>>(xm, qwt, C_, C_, qf, nullptr, nullptr, nullptr, nullptr, 0);
  gemm_bt<0><<<dim3(C_/128, M_/128), 256, 0, stream>>>(xm, kwt, C_, C_, kf, nullptr, nullptr, nullptr, nullptr, 0);
  gemm_bt<0><<<dim3(C_/128, M_/128), 256, 0, stream>>>(xm, vwt, C_, C_, vf, nullptr, nullptr, nullptr, nullptr, 0);

  // 5. RMSNorm q,k -> bf16 ; transpose v -> bf16
  rms_cast<<<dim3(M_), 256, 0, stream>>>(qf, qn_w, qbb);
  rms_cast<<<dim3(M_), 256, 0, stream>>>(kf, kn_w, kbb);
  v_transpose<<<dim3(L_/32, D_/32, B_*H_), 256, 0, stream>>>(vf, vtt);

  // 6. causal flash attention
  attn<<<dim3(L_/16, B_*H_), 64, 0, stream>>>(qbb, kbb, vtt, attn_o);

  // 7. proj + residual + gate: txt2 = txt + g1*(attn@proj)
  gemm_bt<2><<<dim3(C_/128, M_/128), 256, 0, stream>>>(attn_o, pwt, C_, C_, txt2, nullptr, nullptr, txt, mod, 2*C_);

  // 8. LN2 + modulate
  ln_mod<<<dim3(M_), 256, 0, stream>>>(txt2, mod, x2m, 3*C_, 4*C_);

  // 9. fc1 + bias + gelu -> bf16
  gemm_bt<1><<<dim3(CM_/128, M_/128), 256, 0, stream>>>(x2m, f1wt, CM_, C_, nullptr, h1, fc1_b, nullptr, nullptr, 0);

  // 10. fc2 + bias, residual + gate -> d_out (f32)
  gemm_bt<3><<<dim3(C_/128, M_/128), 256, 0, stream>>>(h1, f2wt, C_, CM_, out, nullptr, fc2_b, txt2, mod, 5*C_);
}

// Round 3
// 1322.419 us; speedup vs baseline: 1.1983x; 1.1983x over previous
//
#include <hip/hip_runtime.h>
#include <math.h>

typedef unsigned short u16;
typedef unsigned int   u32;
typedef __attribute__((ext_vector_type(8))) short short8;
typedef __attribute__((ext_vector_type(4))) float f32x4;

#define H_   16
#define B_   2
#define L_   2048
#define C_   2048
#define D_   128
#define CM_  8192
#define SIXC_ (6*C_)
#define M_   (B_*L_)

__device__ __forceinline__ u16 f2bf(float f) {
  u32 u = __float_as_uint(f);
  u = (u + 0x7fffu + ((u >> 16) & 1u)) >> 16;
  return (u16)u;
}

// ---------------- weight transpose+cast: W f32 [K][N] -> Wt bf16 [N][K] ----
__global__ __launch_bounds__(256)
void wt_transpose(const float* __restrict__ Wf, u16* __restrict__ Wt, int K, int N)
{
  __shared__ float tile[32][33];
  const int n0 = blockIdx.x * 32, k0 = blockIdx.y * 32;
  const int t = threadIdx.x;
  const int r = t >> 5, c = t & 31;
  #pragma unroll
  for (int i = 0; i < 4; i++)
    tile[i*8 + r][c] = Wf[(long)(k0 + i*8 + r)*N + n0 + c];
  __syncthreads();
  #pragma unroll
  for (int i = 0; i < 4; i++)
    Wt[(long)(n0 + i*8 + r)*K + k0 + c] = f2bf(tile[c][i*8 + r]);
}

// ---------------- V transpose: vf f32 [B][L][H][D] -> vt bf16 [B][H][D][L] --
__global__ __launch_bounds__(256)
void v_transpose(const float* __restrict__ vf, u16* __restrict__ vt)
{
  __shared__ float tile[32][33];
  const int l0 = blockIdx.x * 32, d0 = blockIdx.y * 32;
  const int bh = blockIdx.z;
  const int b = bh >> 4, h = bh & 15;
  const int t = threadIdx.x;
  const int r = t >> 5, c = t & 31;
  #pragma unroll
  for (int i = 0; i < 4; i++)
    tile[i*8 + r][c] = vf[(((long)b*L_ + l0 + i*8 + r)*H_ + h)*D_ + d0 + c];
  __syncthreads();
  #pragma unroll
  for (int i = 0; i < 4; i++)
    vt[((long)bh*D_ + d0 + i*8 + r)*L_ + l0 + c] = f2bf(tile[c][i*8 + r]);
}

// ---------------- mod = silu(vec) @ mod_w + mod_b --------------------------
__global__ __launch_bounds__(256)
void mod_init(const float* __restrict__ mb, float* __restrict__ mod)
{
  int i = blockIdx.x * 256 + threadIdx.x;           // 0 .. B*6C-1
  mod[i] = mb[i % SIXC_];
}

__global__ __launch_bounds__(256)
void mod_accum(const float* __restrict__ vec, const float* __restrict__ mw,
               float* __restrict__ mod)
{
  const int j  = blockIdx.x * 256 + threadIdx.x;    // 0..6C-1
  const int c0 = blockIdx.y * 128;
  const int b  = blockIdx.z;
  float s = 0.f;
  for (int c = c0; c < c0 + 128; c++) {
    float v  = vec[b*C_ + c];
    float sv = v / (1.0f + expf(-v));
    s += sv * mw[(long)c*SIXC_ + j];
  }
  atomicAdd(&mod[b*SIXC_ + j], s);
}

// ---------------- LayerNorm + modulate -> bf16 -----------------------------
__global__ __launch_bounds__(256)
void ln_mod(const float* __restrict__ x, const float* __restrict__ mod,
            u16* __restrict__ out, int sh_off, int sc_off)
{
  const int row = blockIdx.x;          // 0..M-1
  const int b   = row >> 11;           // row / L
  const int t   = threadIdx.x;
  const int l   = t & 63, w = t >> 6;
  const float* xr = x + (long)row * C_;
  float4 v0 = *(const float4*)(xr + t*8);
  float4 v1 = *(const float4*)(xr + t*8 + 4);
  float xs[8] = {v0.x, v0.y, v0.z, v0.w, v1.x, v1.y, v1.z, v1.w};
  float s = 0.f;
  #pragma unroll
  for (int i = 0; i < 8; i++) s += xs[i];
  #pragma unroll
  for (int o = 1; o < 64; o <<= 1) s += __shfl_xor(s, o, 64);
  __shared__ float r1[4], r2[4];
  if (l == 0) r1[w] = s;
  __syncthreads();
  float mu = (r1[0] + r1[1] + r1[2] + r1[3]) * (1.0f / C_);
  float vs = 0.f;
  #pragma unroll
  for (int i = 0; i < 8; i++) { float d = xs[i] - mu; vs += d*d; }
  #pragma unroll
  for (int o = 1; o < 64; o <<= 1) vs += __shfl_xor(vs, o, 64);
  if (l == 0) r2[w] = vs;
  __syncthreads();
  float var  = (r2[0] + r2[1] + r2[2] + r2[3]) * (1.0f / C_);
  float rstd = rsqrtf(var + 1e-6f);
  const float* shp = mod + b*SIXC_ + sh_off;
  const float* scp = mod + b*SIXC_ + sc_off;
  u16 o8[8];
  #pragma unroll
  for (int i = 0; i < 8; i++) {
    int col = t*8 + i;
    o8[i] = f2bf((xs[i] - mu)*rstd*(1.0f + scp[col]) + shp[col]);
  }
  *(short8*)(out + (long)row*C_ + t*8) = *(short8*)o8;
}

// ---------------- per-head RMSNorm (D=128) f32 -> bf16 ---------------------
__global__ __launch_bounds__(256)
void rms_cast(const float* __restrict__ in, const float* __restrict__ w,
              u16* __restrict__ out)
{
  const int row = blockIdx.x;
  const int t   = threadIdx.x;
  const long base = (long)row*C_ + t*8;
  float4 v0 = *(const float4*)(in + base);
  float4 v1 = *(const float4*)(in + base + 4);
  float xs[8] = {v0.x, v0.y, v0.z, v0.w, v1.x, v1.y, v1.z, v1.w};
  float ss = 0.f;
  #pragma unroll
  for (int i = 0; i < 8; i++) ss += xs[i]*xs[i];
  #pragma unroll
  for (int o = 1; o < 16; o <<= 1) ss += __shfl_xor(ss, o, 64);
  float sc = rsqrtf(ss * (1.0f/D_) + 1e-6f);
  const int d0 = (t & 15) * 8;
  u16 o8[8];
  #pragma unroll
  for (int i = 0; i < 8; i++) o8[i] = f2bf(xs[i]*sc*w[d0 + i]);
  *(short8*)(out + base) = *(short8*)o8;
}

// ---------------- GEMM: A[M,K] bf16 x Bt[N,K] bf16 -> C[M,N] ---------------
// Staging via global_load_lds width=16 (m97 structure).
// MODE 0: C f32 = acc
// MODE 1: C bf16 = gelu_tanh(acc + bias[n])
// MODE 2: C f32 = resid + mod[b,goff+n]*acc
// MODE 3: C f32 = resid + mod[b,goff+n]*(acc + bias[n])
template<int MODE>
__global__ __launch_bounds__(256)
void gemm_bt(const u16* __restrict__ A, const u16* __restrict__ Bt,
             int N, int K,
             float* __restrict__ Cf, u16* __restrict__ Cb,
             const float* __restrict__ bias,
             const float* __restrict__ resid,
             const float* __restrict__ mod, int goff)
{
  // linear [128][32] bf16 tiles: row stride 64B, 4 lanes x 16B per row
  __shared__ __attribute__((aligned(16))) u16 As[128*32];
  __shared__ __attribute__((aligned(16))) u16 Bs[128*32];
  const int tid = threadIdx.x;
  const int l   = tid & 63;
  const int llo = l & 15, lhi = l >> 4;
  const int w   = tid >> 6;
  const int m0 = blockIdx.y * 128, n0 = blockIdx.x * 128;
  const int wm = (w >> 1) * 64, wn = (w & 1) * 64;

  const u16* Ag = A  + (long)m0 * K;
  const u16* Bg = Bt + (long)n0 * K;

  // per-lane staging source offsets: wave w covers chunks {2w, 2w+1};
  // chunk ch = rows [16*ch, 16*ch+16); lane l -> row 16*ch + (l>>2), k-elems (l&3)*8
  const int srow0 = (w*2)*16 + (l >> 2);
  const int skoff = (l & 3) * 8;

  f32x4 acc[4][4];
  #pragma unroll
  for (int i = 0; i < 4; i++)
    #pragma unroll
    for (int j = 0; j < 4; j++) acc[i][j] = (f32x4){0.f, 0.f, 0.f, 0.f};

  for (int k0 = 0; k0 < K; k0 += 32) {
    __syncthreads();
    #pragma unroll
    for (int i = 0; i < 2; i++) {
      const u16* ga = Ag + (long)(srow0 + i*16)*K + k0 + skoff;
      const u16* gb = Bg + (long)(srow0 + i*16)*K + k0 + skoff;
      __builtin_amdgcn_global_load_lds(
          (const __attribute__((address_space(1))) void*)ga,
          (__attribute__((address_space(3))) void*)(As + (w*2 + i)*512), 16, 0, 0);
      __builtin_amdgcn_global_load_lds(
          (const __attribute__((address_space(1))) void*)gb,
          (__attribute__((address_space(3))) void*)(Bs + (w*2 + i)*512), 16, 0, 0);
    }
    __syncthreads();
    short8 a[4], b[4];
    #pragma unroll
    for (int f = 0; f < 4; f++) {
      a[f] = *(const short8*)&As[(wm + f*16 + llo)*32 + lhi*8];
      b[f] = *(const short8*)&Bs[(wn + f*16 + llo)*32 + lhi*8];
    }
    #pragma unroll
    for (int mf = 0; mf < 4; mf++)
      #pragma unroll
      for (int nf = 0; nf < 4; nf++)
        acc[mf][nf] = __builtin_amdgcn_mfma_f32_16x16x32_bf16(a[mf], b[nf], acc[mf][nf], 0, 0, 0);
  }

  #pragma unroll
  for (int mf = 0; mf < 4; mf++) {
    #pragma unroll
    for (int j = 0; j < 4; j++) {
      const int  r  = m0 + wm + mf*16 + lhi*4 + j;
      const long rb = (long)r * N;
      const int  bb = r >> 11;               // row / L (only valid when N==C_)
      #pragma unroll
      for (int nf = 0; nf < 4; nf++) {
        const int col = n0 + wn + nf*16 + llo;
        float x = acc[mf][nf][j];
        if (MODE == 0) {
          Cf[rb + col] = x;
        } else if (MODE == 1) {
          x += bias[col];
          float g = 0.5f*x*(1.0f + tanhf(0.7978845608028654f*(x + 0.044715f*x*x*x)));
          Cb[rb + col] = f2bf(g);
        } else if (MODE == 2) {
          Cf[rb + col] = resid[rb + col] + mod[bb*SIXC_ + goff + col] * x;
        } else {
          Cf[rb + col] = resid[rb + col] + mod[bb*SIXC_ + goff + col] * (x + bias[col]);
        }
      }
    }
  }
}

// ---------------- causal flash attention -----------------------------------
// qb,kb: [B][L][H][D] bf16 ; vt: [B][H][D][L] bf16 ; out: [B][L][C] bf16
// 4 independent waves per block; wave handles the causal-balanced q-tile
// pair (p, 127-p) -> uniform work; private P-buffer, no block barriers.
__global__ __launch_bounds__(256)
void attn(const u16* __restrict__ qb, const u16* __restrict__ kb,
          const u16* __restrict__ vt, u16* __restrict__ out)
{
  const int w = threadIdx.x >> 6;
  const int l = threadIdx.x & 63;
  const int p  = blockIdx.x * 4 + w;       // pair index 0..63
  const int bh = blockIdx.y;
  const int b = bh >> 4, h = bh & 15;
  const int llo = l & 15, lhi = l >> 4;

  __shared__ __attribute__((aligned(16))) u16 Plds[4][16*32];
  u16* Pl = &Plds[w][0];

  const u16* kbase = kb + ((long)b*L_*H_ + h)*D_;
  const u16* vbase = vt + (long)bh*D_*L_;
  const float scale = 0.08838834764831845f;   // 1/sqrt(128)

  #pragma unroll
  for (int pass = 0; pass < 2; pass++) {
    const int qt = pass ? (127 - p) : p;
    const int q0 = qt * 16;

    short8 qf[4];
    const u16* qrow = qb + (((long)b*L_ + q0 + llo)*H_ + h)*D_;
    #pragma unroll
    for (int dc = 0; dc < 4; dc++) qf[dc] = *(const short8*)(qrow + dc*32 + lhi*8);

    f32x4 o[8];
    #pragma unroll
    for (int f = 0; f < 8; f++) o[f] = (f32x4){0.f, 0.f, 0.f, 0.f};
    float mreg = -1e30f, lsum = 0.f;

    const int ntiles = (q0 + 16 + 31) >> 5;

    for (int kt = 0; kt < ntiles; kt++) {
      const int kv0 = kt * 32;
      f32x4 st[2];
      st[0] = (f32x4){0.f,0.f,0.f,0.f};
      st[1] = (f32x4){0.f,0.f,0.f,0.f};
      #pragma unroll
      for (int mf = 0; mf < 2; mf++) {
        const u16* krow = kbase + (long)(kv0 + mf*16 + llo)*(H_*D_);
        #pragma unroll
        for (int dc = 0; dc < 4; dc++) {
          short8 kfr = *(const short8*)(krow + dc*32 + lhi*8);
          st[mf] = __builtin_amdgcn_mfma_f32_16x16x32_bf16(kfr, qf[dc], st[mf], 0, 0, 0);
        }
      }
      const int qcol = q0 + llo;
      float sv[8];
      float tmax = -1e30f;
      #pragma unroll
      for (int mf = 0; mf < 2; mf++)
        #pragma unroll
        for (int j = 0; j < 4; j++) {
          int key = kv0 + mf*16 + lhi*4 + j;
          float x = st[mf][j] * scale;
          x = (key > qcol) ? -1e30f : x;
          sv[mf*4 + j] = x;
          tmax = fmaxf(tmax, x);
        }
      tmax = fmaxf(tmax, __shfl_xor(tmax, 16, 64));
      tmax = fmaxf(tmax, __shfl_xor(tmax, 32, 64));
      float mnew  = fmaxf(mreg, tmax);
      float alpha = __expf(mreg - mnew);
      float psum = 0.f;
      u16 pb[8];
      #pragma unroll
      for (int i = 0; i < 8; i++) {
        float pp = __expf(sv[i] - mnew);
        psum += pp;
        pb[i] = f2bf(pp);
      }
      psum += __shfl_xor(psum, 16, 64);
      psum += __shfl_xor(psum, 32, 64);
      lsum = lsum*alpha + psum;
      mreg = mnew;
      #pragma unroll
      for (int j = 0; j < 4; j++) {
        float aj = __shfl(alpha, lhi*4 + j, 64);
        #pragma unroll
        for (int f = 0; f < 8; f++) o[f][j] *= aj;
      }
      // P^T -> LDS as P[q][key_rel] (16x32 bf16), packed pairs
      #pragma unroll
      for (int mf = 0; mf < 2; mf++) {
        u32 w0 = (u32)pb[mf*4+0] | ((u32)pb[mf*4+1] << 16);
        u32 w1 = (u32)pb[mf*4+2] | ((u32)pb[mf*4+3] << 16);
        *(u32*)&Pl[llo*32 + mf*16 + lhi*4]     = w0;
        *(u32*)&Pl[llo*32 + mf*16 + lhi*4 + 2] = w1;
      }
      // wave-local visibility: drain DS ops, forbid compiler reordering
      asm volatile("s_waitcnt lgkmcnt(0)" ::: "memory");
      short8 pf = *(const short8*)&Pl[llo*32 + lhi*8];
      #pragma unroll
      for (int f = 0; f < 8; f++) {
        short8 vfr = *(const short8*)(vbase + (long)(f*16 + llo)*L_ + kv0 + lhi*8);
        o[f] = __builtin_amdgcn_mfma_f32_16x16x32_bf16(pf, vfr, o[f], 0, 0, 0);
      }
      // ensure P reads complete before next tile's overwrite
      asm volatile("s_waitcnt lgkmcnt(0)" ::: "memory");
    }

    #pragma unroll
    for (int j = 0; j < 4; j++) {
      float lq  = __shfl(lsum, lhi*4 + j, 64);
      float inv = 1.0f / lq;
      const int qr = q0 + lhi*4 + j;
      u16* orow = out + ((long)b*L_ + qr)*C_ + h*D_;
      #pragma unroll
      for (int f = 0; f < 8; f++)
        orow[f*16 + llo] = f2bf(o[f][j] * inv);
    }
  }
}

// ---------------------------------------------------------------------------
extern "C" void kernel_launch(void* const* d_in, const int* in_sizes, int n_in,
                              void* d_out, int out_size, void* d_ws, size_t ws_size,
                              hipStream_t stream)
{
  const float* txt    = (const float*)d_in[0];
  const float* vec    = (const float*)d_in[1];
  const float* mod_w  = (const float*)d_in[2];
  const float* mod_b  = (const float*)d_in[3];
  const float* q_w    = (const float*)d_in[4];
  const float* k_w    = (const float*)d_in[5];
  const float* v_w    = (const float*)d_in[6];
  const float* qn_w   = (const float*)d_in[7];
  const float* kn_w   = (const float*)d_in[8];
  const float* proj_w = (const float*)d_in[9];
  const float* fc1_w  = (const float*)d_in[10];
  const float* fc1_b  = (const float*)d_in[11];
  const float* fc2_w  = (const float*)d_in[12];
  const float* fc2_b  = (const float*)d_in[13];
  float* out = (float*)d_out;

  char* ws = (char*)d_ws;
  size_t off = 0;
  auto alloc = [&](size_t bytes) {
    size_t r = off; off += (bytes + 255) & ~(size_t)255; return r;
  };
  float* mod  = (float*)(ws + alloc((size_t)B_*SIXC_*4));
  u16*  qwt   = (u16*)(ws + alloc((size_t)C_*C_*2));
  u16*  kwt   = (u16*)(ws + alloc((size_t)C_*C_*2));
  u16*  vwt   = (u16*)(ws + alloc((size_t)C_*C_*2));
  u16*  pwt   = (u16*)(ws + alloc((size_t)C_*C_*2));
  u16*  f1wt  = (u16*)(ws + alloc((size_t)C_*CM_*2));
  u16*  f2wt  = (u16*)(ws + alloc((size_t)C_*CM_*2));
  u16*  xm    = (u16*)(ws + alloc((size_t)M_*C_*2));   // later reused: attn_out
  float* qf   = (float*)(ws + alloc((size_t)M_*C_*4)); // later reused: txt2
  float* kf   = (float*)(ws + alloc((size_t)M_*C_*4)); // later reused: h1 (spans kf+vf)
  float* vf   = (float*)(ws + alloc((size_t)M_*C_*4));
  u16*  qbb   = (u16*)(ws + alloc((size_t)M_*C_*2));   // later reused: x2m
  u16*  kbb   = (u16*)(ws + alloc((size_t)M_*C_*2));
  u16*  vtt   = (u16*)(ws + alloc((size_t)M_*C_*2));
  u16*   h1     = (u16*)kf;
  float* txt2   = qf;
  u16*   x2m    = qbb;
  u16*   attn_o = xm;

  // 1. weight cast+transpose (f32 [K][N] -> bf16 [N][K])
  wt_transpose<<<dim3(C_/32,  C_/32 ), 256, 0, stream>>>(q_w,    qwt,  C_,  C_);
  wt_transpose<<<dim3(C_/32,  C_/32 ), 256, 0, stream>>>(k_w,    kwt,  C_,  C_);
  wt_transpose<<<dim3(C_/32,  C_/32 ), 256, 0, stream>>>(v_w,    vwt,  C_,  C_);
  wt_transpose<<<dim3(C_/32,  C_/32 ), 256, 0, stream>>>(proj_w, pwt,  C_,  C_);
  wt_transpose<<<dim3(CM_/32, C_/32 ), 256, 0, stream>>>(fc1_w,  f1wt, C_,  CM_);
  wt_transpose<<<dim3(C_/32,  CM_/32), 256, 0, stream>>>(fc2_w,  f2wt, CM_, C_);

  // 2. modulation vector
  mod_init <<<dim3(B_*SIXC_/256), 256, 0, stream>>>(mod_b, mod);
  mod_accum<<<dim3(SIXC_/256, C_/128, B_), 256, 0, stream>>>(vec, mod_w, mod);

  // 3. LN1 + modulate
  ln_mod<<<dim3(M_), 256, 0, stream>>>(txt, mod, xm, 0, C_);

  // 4. QKV GEMMs (f32 out)
  gemm_bt<0><<<dim3(C_/128, M_/128), 256, 0, stream>>>(xm, qwt, C_, C_, qf, nullptr, nullptr, nullptr, nullptr, 0);
  gemm_bt<0><<<dim3(C_/128, M_/128), 256, 0, stream>>>(xm, kwt, C_, C_, kf, nullptr, nullptr, nullptr, nullptr, 0);
  gemm_bt<0><<<dim3(C_/128, M_/128), 256, 0, stream>>>(xm, vwt, C_, C_, vf, nullptr, nullptr, nullptr, nullptr, 0);

  // 5. RMSNorm q,k -> bf16 ; transpose v -> bf16
  rms_cast<<<dim3(M_), 256, 0, stream>>>(qf, qn_w, qbb);
  rms_cast<<<dim3(M_), 256, 0, stream>>>(kf, kn_w, kbb);
  v_transpose<<<dim3(L_/32, D_/32, B_*H_), 256, 0, stream>>>(vf, vtt);

  // 6. causal flash attention (pair-balanced, 4 waves/block)
  attn<<<dim3(L_/16/4/2, B_*H_), 256, 0, stream>>>(qbb, kbb, vtt, attn_o);

  // 7. proj + residual + gate: txt2 = txt + g1*(attn@proj)
  gemm_bt<2><<<dim3(C_/128, M_/128), 256, 0, stream>>>(attn_o, pwt, C_, C_, txt2, nullptr, nullptr, txt, mod, 2*C_);

  // 8. LN2 + modulate
  ln_mod<<<dim3(M_), 256, 0, stream>>>(txt2, mod, x2m, 3*C_, 4*C_);

  // 9. fc1 + bias + gelu -> bf16
  gemm_bt<1><<<dim3(CM_/128, M_/128), 256, 0, stream>>>(x2m, f1wt, CM_, C_, nullptr, h1, fc1_b, nullptr, nullptr, 0);

  // 10. fc2 + bias, residual + gate -> d_out (f32)
  gemm_bt<3><<<dim3(C_/128, M_/128), 256, 0, stream>>>(h1, f2wt, C_, CM_, out, nullptr, fc2_b, txt2, mod, 5*C_);
}

// Round 6
// 1250.955 us; speedup vs baseline: 1.2667x; 1.0571x over previous
//
#include <hip/hip_runtime.h>
#include <math.h>

typedef unsigned short u16;
typedef unsigned int   u32;
typedef __attribute__((ext_vector_type(8))) short short8;
typedef __attribute__((ext_vector_type(4))) float f32x4;

#define H_   16
#define B_   2
#define L_   2048
#define C_   2048
#define D_   128
#define CM_  8192
#define SIXC_ (6*C_)
#define M_   (B_*L_)

__device__ __forceinline__ u16 f2bf(float f) {
  u32 u = __float_as_uint(f);
  u = (u + 0x7fffu + ((u >> 16) & 1u)) >> 16;
  return (u16)u;
}

// ---------------- weight transpose+cast: W f32 [K][N] -> Wt bf16 [N][K] ----
__global__ __launch_bounds__(256)
void wt_transpose(const float* __restrict__ Wf, u16* __restrict__ Wt, int K, int N)
{
  __shared__ float tile[32][33];
  const int n0 = blockIdx.x * 32, k0 = blockIdx.y * 32;
  const int t = threadIdx.x;
  const int r = t >> 5, c = t & 31;
  #pragma unroll
  for (int i = 0; i < 4; i++)
    tile[i*8 + r][c] = Wf[(long)(k0 + i*8 + r)*N + n0 + c];
  __syncthreads();
  #pragma unroll
  for (int i = 0; i < 4; i++)
    Wt[(long)(n0 + i*8 + r)*K + k0 + c] = f2bf(tile[c][i*8 + r]);
}

// ---------------- V transpose: vf f32 [B][L][H][D] -> vp swizzled ----------
// vp layout: [bh][kt=l/32][f=d/16][lhi=(l%32)/8][llo=d%16][e=l%8]
// so attn's PV fragment load is vp_base + lane*8 (coalesced 1KB/wave).
__global__ __launch_bounds__(256)
void v_transpose(const float* __restrict__ vf, u16* __restrict__ vp)
{
  __shared__ float tile[32][33];
  const int l0 = blockIdx.x * 32, d0 = blockIdx.y * 32;
  const int bh = blockIdx.z;
  const int b = bh >> 4, h = bh & 15;
  const int t = threadIdx.x;
  const int r = t >> 5, c = t & 31;
  #pragma unroll
  for (int i = 0; i < 4; i++)
    tile[i*8 + r][c] = vf[(((long)b*L_ + l0 + i*8 + r)*H_ + h)*D_ + d0 + c];
  __syncthreads();
  if (t < 128) {
    const int dl  = t >> 2;        // d_local 0..31
    const int oct = t & 3;         // lhi (l-octet)
    const int d   = d0 + dl;
    const int f   = d >> 4, vllo = d & 15;
    const int kt  = l0 >> 5;
    u16 o8[8];
    #pragma unroll
    for (int e = 0; e < 8; e++) o8[e] = f2bf(tile[oct*8 + e][dl]);
    u16* dst = vp + (((((long)bh*64 + kt)*8 + f)*4 + oct)*16 + vllo)*8;
    *(short8*)dst = *(short8*)o8;
  }
}

// ---------------- mod = silu(vec) @ mod_w + mod_b --------------------------
__global__ __launch_bounds__(256)
void mod_init(const float* __restrict__ mb, float* __restrict__ mod)
{
  int i = blockIdx.x * 256 + threadIdx.x;           // 0 .. B*6C-1
  mod[i] = mb[i % SIXC_];
}

__global__ __launch_bounds__(256)
void mod_accum(const float* __restrict__ vec, const float* __restrict__ mw,
               float* __restrict__ mod)
{
  const int j  = blockIdx.x * 256 + threadIdx.x;    // 0..6C-1
  const int c0 = blockIdx.y * 128;
  const int b  = blockIdx.z;
  float s = 0.f;
  for (int c = c0; c < c0 + 128; c++) {
    float v  = vec[b*C_ + c];
    float sv = v / (1.0f + expf(-v));
    s += sv * mw[(long)c*SIXC_ + j];
  }
  atomicAdd(&mod[b*SIXC_ + j], s);
}

// ---------------- LayerNorm + modulate -> bf16 -----------------------------
__global__ __launch_bounds__(256)
void ln_mod(const float* __restrict__ x, const float* __restrict__ mod,
            u16* __restrict__ out, int sh_off, int sc_off)
{
  const int row = blockIdx.x;          // 0..M-1
  const int b   = row >> 11;           // row / L
  const int t   = threadIdx.x;
  const int l   = t & 63, w = t >> 6;
  const float* xr = x + (long)row * C_;
  float4 v0 = *(const float4*)(xr + t*8);
  float4 v1 = *(const float4*)(xr + t*8 + 4);
  float xs[8] = {v0.x, v0.y, v0.z, v0.w, v1.x, v1.y, v1.z, v1.w};
  float s = 0.f;
  #pragma unroll
  for (int i = 0; i < 8; i++) s += xs[i];
  #pragma unroll
  for (int o = 1; o < 64; o <<= 1) s += __shfl_xor(s, o, 64);
  __shared__ float r1[4], r2[4];
  if (l == 0) r1[w] = s;
  __syncthreads();
  float mu = (r1[0] + r1[1] + r1[2] + r1[3]) * (1.0f / C_);
  float vs = 0.f;
  #pragma unroll
  for (int i = 0; i < 8; i++) { float d = xs[i] - mu; vs += d*d; }
  #pragma unroll
  for (int o = 1; o < 64; o <<= 1) vs += __shfl_xor(vs, o, 64);
  if (l == 0) r2[w] = vs;
  __syncthreads();
  float var  = (r2[0] + r2[1] + r2[2] + r2[3]) * (1.0f / C_);
  float rstd = rsqrtf(var + 1e-6f);
  const float* shp = mod + b*SIXC_ + sh_off;
  const float* scp = mod + b*SIXC_ + sc_off;
  u16 o8[8];
  #pragma unroll
  for (int i = 0; i < 8; i++) {
    int col = t*8 + i;
    o8[i] = f2bf((xs[i] - mu)*rstd*(1.0f + scp[col]) + shp[col]);
  }
  *(short8*)(out + (long)row*C_ + t*8) = *(short8*)o8;
}

// ---------------- per-head RMSNorm f32 -> bf16, swizzled QS layout ---------
// QS layout: [bh][g=l/16][dc=d/32][lhi=(d%32)/8][llo=l%16][e=d%8]
// so attn's QK fragment load is base + lane*8 (coalesced 1KB/wave).
__global__ __launch_bounds__(256)
void rms_swz(const float* __restrict__ in, const float* __restrict__ w,
             u16* __restrict__ out)
{
  const int row = blockIdx.x;          // (b,l)
  const int b = row >> 11, lseq = row & 2047;
  const int g = lseq >> 4, llo = lseq & 15;
  const int t   = threadIdx.x;
  const int h   = t >> 4, c16 = t & 15;
  const int dc  = c16 >> 2, lhi = c16 & 3;
  const long base = (long)row*C_ + t*8;
  float4 v0 = *(const float4*)(in + base);
  float4 v1 = *(const float4*)(in + base + 4);
  float xs[8] = {v0.x, v0.y, v0.z, v0.w, v1.x, v1.y, v1.z, v1.w};
  float ss = 0.f;
  #pragma unroll
  for (int i = 0; i < 8; i++) ss += xs[i]*xs[i];
  #pragma unroll
  for (int o = 1; o < 16; o <<= 1) ss += __shfl_xor(ss, o, 64);
  float sc = rsqrtf(ss * (1.0f/D_) + 1e-6f);
  const int d0 = c16 * 8;
  u16 o8[8];
  #pragma unroll
  for (int i = 0; i < 8; i++) o8[i] = f2bf(xs[i]*sc*w[d0 + i]);
  u16* dst = out + (((((long)(b*H_ + h)*128 + g)*4 + dc)*4 + lhi)*16 + llo)*8;
  *(short8*)dst = *(short8*)o8;
}

// ---------------- GEMM: A[M,K] bf16 x Bt[N,K] bf16 -> C[M,N] ---------------
// Staging via global_load_lds width=16 (m97 structure).
template<int MODE>
__global__ __launch_bounds__(256)
void gemm_bt(const u16* __restrict__ A, const u16* __restrict__ Bt,
             int N, int K,
             float* __restrict__ Cf, u16* __restrict__ Cb,
             const float* __restrict__ bias,
             const float* __restrict__ resid,
             const float* __restrict__ mod, int goff)
{
  __shared__ __attribute__((aligned(16))) u16 As[128*32];
  __shared__ __attribute__((aligned(16))) u16 Bs[128*32];
  const int tid = threadIdx.x;
  const int l   = tid & 63;
  const int llo = l & 15, lhi = l >> 4;
  const int w   = tid >> 6;
  const int m0 = blockIdx.y * 128, n0 = blockIdx.x * 128;
  const int wm = (w >> 1) * 64, wn = (w & 1) * 64;

  const u16* Ag = A  + (long)m0 * K;
  const u16* Bg = Bt + (long)n0 * K;

  const int srow0 = (w*2)*16 + (l >> 2);
  const int skoff = (l & 3) * 8;

  f32x4 acc[4][4];
  #pragma unroll
  for (int i = 0; i < 4; i++)
    #pragma unroll
    for (int j = 0; j < 4; j++) acc[i][j] = (f32x4){0.f, 0.f, 0.f, 0.f};

  for (int k0 = 0; k0 < K; k0 += 32) {
    __syncthreads();
    #pragma unroll
    for (int i = 0; i < 2; i++) {
      const u16* ga = Ag + (long)(srow0 + i*16)*K + k0 + skoff;
      const u16* gb = Bg + (long)(srow0 + i*16)*K + k0 + skoff;
      __builtin_amdgcn_global_load_lds(
          (const __attribute__((address_space(1))) void*)ga,
          (__attribute__((address_space(3))) void*)(As + (w*2 + i)*512), 16, 0, 0);
      __builtin_amdgcn_global_load_lds(
          (const __attribute__((address_space(1))) void*)gb,
          (__attribute__((address_space(3))) void*)(Bs + (w*2 + i)*512), 16, 0, 0);
    }
    __syncthreads();
    short8 a[4], b[4];
    #pragma unroll
    for (int f = 0; f < 4; f++) {
      a[f] = *(const short8*)&As[(wm + f*16 + llo)*32 + lhi*8];
      b[f] = *(const short8*)&Bs[(wn + f*16 + llo)*32 + lhi*8];
    }
    #pragma unroll
    for (int mf = 0; mf < 4; mf++)
      #pragma unroll
      for (int nf = 0; nf < 4; nf++)
        acc[mf][nf] = __builtin_amdgcn_mfma_f32_16x16x32_bf16(a[mf], b[nf], acc[mf][nf], 0, 0, 0);
  }

  #pragma unroll
  for (int mf = 0; mf < 4; mf++) {
    #pragma unroll
    for (int j = 0; j < 4; j++) {
      const int  r  = m0 + wm + mf*16 + lhi*4 + j;
      const long rb = (long)r * N;
      const int  bb = r >> 11;
      #pragma unroll
      for (int nf = 0; nf < 4; nf++) {
        const int col = n0 + wn + nf*16 + llo;
        float x = acc[mf][nf][j];
        if (MODE == 0) {
          Cf[rb + col] = x;
        } else if (MODE == 1) {
          x += bias[col];
          float g = 0.5f*x*(1.0f + tanhf(0.7978845608028654f*(x + 0.044715f*x*x*x)));
          Cb[rb + col] = f2bf(g);
        } else if (MODE == 2) {
          Cf[rb + col] = resid[rb + col] + mod[bb*SIXC_ + goff + col] * x;
        } else {
          Cf[rb + col] = resid[rb + col] + mod[bb*SIXC_ + goff + col] * (x + bias[col]);
        }
      }
    }
  }
}

// ---------------- causal flash attention -----------------------------------
// qs,ks: QS swizzled layout; vp: V swizzled layout; out: [B][L][C] bf16
// one wave per q-tile (16 rows); qt descending (longest-first);
// all fragment loads are base + lane*16B (coalesced).
__global__ __launch_bounds__(256, 4)
void attn(const u16* __restrict__ qs, const u16* __restrict__ ks,
          const u16* __restrict__ vp, u16* __restrict__ out)
{
  const int w = threadIdx.x >> 6;
  const int l = threadIdx.x & 63;
  const int qt = 127 - (blockIdx.x * 4 + w);   // descending
  const int bh = blockIdx.y;
  const int b = bh >> 4;
  const int h = bh & 15;
  const int llo = l & 15, lhi = l >> 4;

  __shared__ __attribute__((aligned(16))) u16 Plds[4][16*32];
  u16* Pl = &Plds[w][0];

  const u16* qbase = qs + ((long)bh*128 + qt)*2048;
  const u16* kbase = ks + (long)bh*262144;     // 128 g * 2048
  const u16* vbase = vp + (long)bh*262144;     // 64 kt * 4096
  const float scale = 0.08838834764831845f;    // 1/sqrt(128)

  short8 qf[4];
  #pragma unroll
  for (int dc = 0; dc < 4; dc++)
    qf[dc] = *(const short8*)(qbase + dc*512 + l*8);

  f32x4 o[8];
  #pragma unroll
  for (int f = 0; f < 8; f++) o[f] = (f32x4){0.f, 0.f, 0.f, 0.f};
  float mreg = -1e30f, lsum = 0.f;

  const int ntiles = (qt + 2) >> 1;
  const int qcol = qt*16 + llo;

  for (int kt = 0; kt < ntiles; kt++) {
    const int kv0 = kt * 32;
    const u16* ktb = kbase + (long)kt*4096;
    const u16* vtb = vbase + (long)kt*4096;

    f32x4 st[2];
    st[0] = (f32x4){0.f,0.f,0.f,0.f};
    st[1] = (f32x4){0.f,0.f,0.f,0.f};
    #pragma unroll
    for (int mf = 0; mf < 2; mf++) {
      #pragma unroll
      for (int dc = 0; dc < 4; dc++) {
        short8 kfr = *(const short8*)(ktb + mf*2048 + dc*512 + l*8);
        st[mf] = __builtin_amdgcn_mfma_f32_16x16x32_bf16(kfr, qf[dc], st[mf], 0, 0, 0);
      }
    }

    // V prefetch (coalesced; independent of softmax)
    short8 vfr[8];
    #pragma unroll
    for (int f = 0; f < 8; f++)
      vfr[f] = *(const short8*)(vtb + f*512 + l*8);

    float sv[8];
    float tmax = -1e30f;
    #pragma unroll
    for (int mf = 0; mf < 2; mf++)
      #pragma unroll
      for (int j = 0; j < 4; j++) {
        int key = kv0 + mf*16 + lhi*4 + j;
        float x = st[mf][j] * scale;
        x = (key > qcol) ? -1e30f : x;
        sv[mf*4 + j] = x;
        tmax = fmaxf(tmax, x);
      }
    tmax = fmaxf(tmax, __shfl_xor(tmax, 16, 64));
    tmax = fmaxf(tmax, __shfl_xor(tmax, 32, 64));
    float mnew  = fmaxf(mreg, tmax);
    float alpha = __expf(mreg - mnew);
    float psum = 0.f;
    u16 pb[8];
    #pragma unroll
    for (int i = 0; i < 8; i++) {
      float pp = __expf(sv[i] - mnew);
      psum += pp;
      pb[i] = f2bf(pp);
    }
    psum += __shfl_xor(psum, 16, 64);
    psum += __shfl_xor(psum, 32, 64);
    lsum = lsum*alpha + psum;
    mreg = mnew;
    #pragma unroll
    for (int j = 0; j < 4; j++) {
      float aj = __shfl(alpha, lhi*4 + j, 64);
      #pragma unroll
      for (int f = 0; f < 8; f++) o[f][j] *= aj;
    }
    // P^T -> LDS as P[q][key_rel] (16x32 bf16), packed pairs
    #pragma unroll
    for (int mf = 0; mf < 2; mf++) {
      u32 w0 = (u32)pb[mf*4+0] | ((u32)pb[mf*4+1] << 16);
      u32 w1 = (u32)pb[mf*4+2] | ((u32)pb[mf*4+3] << 16);
      *(u32*)&Pl[llo*32 + mf*16 + lhi*4]     = w0;
      *(u32*)&Pl[llo*32 + mf*16 + lhi*4 + 2] = w1;
    }
    asm volatile("s_waitcnt lgkmcnt(0)" ::: "memory");
    short8 pf = *(const short8*)&Pl[llo*32 + lhi*8];
    #pragma unroll
    for (int f = 0; f < 8; f++)
      o[f] = __builtin_amdgcn_mfma_f32_16x16x32_bf16(pf, vfr[f], o[f], 0, 0, 0);
    asm volatile("s_waitcnt lgkmcnt(0)" ::: "memory");
  }

  #pragma unroll
  for (int j = 0; j < 4; j++) {
    float lq  = __shfl(lsum, lhi*4 + j, 64);
    float inv = 1.0f / lq;
    const int qr = qt*16 + lhi*4 + j;
    u16* orow = out + ((long)b*L_ + qr)*C_ + h*D_;
    #pragma unroll
    for (int f = 0; f < 8; f++)
      orow[f*16 + llo] = f2bf(o[f][j] * inv);
  }
}

// ---------------------------------------------------------------------------
extern "C" void kernel_launch(void* const* d_in, const int* in_sizes, int n_in,
                              void* d_out, int out_size, void* d_ws, size_t ws_size,
                              hipStream_t stream)
{
  const float* txt    = (const float*)d_in[0];
  const float* vec    = (const float*)d_in[1];
  const float* mod_w  = (const float*)d_in[2];
  const float* mod_b  = (const float*)d_in[3];
  const float* q_w    = (const float*)d_in[4];
  const float* k_w    = (const float*)d_in[5];
  const float* v_w    = (const float*)d_in[6];
  const float* qn_w   = (const float*)d_in[7];
  const float* kn_w   = (const float*)d_in[8];
  const float* proj_w = (const float*)d_in[9];
  const float* fc1_w  = (const float*)d_in[10];
  const float* fc1_b  = (const float*)d_in[11];
  const float* fc2_w  = (const float*)d_in[12];
  const float* fc2_b  = (const float*)d_in[13];
  float* out = (float*)d_out;

  char* ws = (char*)d_ws;
  size_t off = 0;
  auto alloc = [&](size_t bytes) {
    size_t r = off; off += (bytes + 255) & ~(size_t)255; return r;
  };
  float* mod  = (float*)(ws + alloc((size_t)B_*SIXC_*4));
  u16*  qwt   = (u16*)(ws + alloc((size_t)C_*C_*2));
  u16*  kwt   = (u16*)(ws + alloc((size_t)C_*C_*2));
  u16*  vwt   = (u16*)(ws + alloc((size_t)C_*C_*2));
  u16*  pwt   = (u16*)(ws + alloc((size_t)C_*C_*2));
  u16*  f1wt  = (u16*)(ws + alloc((size_t)C_*CM_*2));
  u16*  f2wt  = (u16*)(ws + alloc((size_t)C_*CM_*2));
  u16*  xm    = (u16*)(ws + alloc((size_t)M_*C_*2));   // later reused: attn_out
  float* qf   = (float*)(ws + alloc((size_t)M_*C_*4)); // later reused: txt2
  float* kf   = (float*)(ws + alloc((size_t)M_*C_*4)); // later reused: h1 (spans kf+vf)
  float* vf   = (float*)(ws + alloc((size_t)M_*C_*4));
  u16*  qbb   = (u16*)(ws + alloc((size_t)M_*C_*2));   // later reused: x2m
  u16*  kbb   = (u16*)(ws + alloc((size_t)M_*C_*2));
  u16*  vtt   = (u16*)(ws + alloc((size_t)M_*C_*2));
  u16*   h1     = (u16*)kf;
  float* txt2   = qf;
  u16*   x2m    = qbb;
  u16*   attn_o = xm;

  // 1. weight cast+transpose (f32 [K][N] -> bf16 [N][K])
  wt_transpose<<<dim3(C_/32,  C_/32 ), 256, 0, stream>>>(q_w,    qwt,  C_,  C_);
  wt_transpose<<<dim3(C_/32,  C_/32 ), 256, 0, stream>>>(k_w,    kwt,  C_,  C_);
  wt_transpose<<<dim3(C_/32,  C_/32 ), 256, 0, stream>>>(v_w,    vwt,  C_,  C_);
  wt_transpose<<<dim3(C_/32,  C_/32 ), 256, 0, stream>>>(proj_w, pwt,  C_,  C_);
  wt_transpose<<<dim3(CM_/32, C_/32 ), 256, 0, stream>>>(fc1_w,  f1wt, C_,  CM_);
  wt_transpose<<<dim3(C_/32,  CM_/32), 256, 0, stream>>>(fc2_w,  f2wt, CM_, C_);

  // 2. modulation vector
  mod_init <<<dim3(B_*SIXC_/256), 256, 0, stream>>>(mod_b, mod);
  mod_accum<<<dim3(SIXC_/256, C_/128, B_), 256, 0, stream>>>(vec, mod_w, mod);

  // 3. LN1 + modulate
  ln_mod<<<dim3(M_), 256, 0, stream>>>(txt, mod, xm, 0, C_);

  // 4. QKV GEMMs (f32 out)
  gemm_bt<0><<<dim3(C_/128, M_/128), 256, 0, stream>>>(xm, qwt, C_, C_, qf, nullptr, nullptr, nullptr, nullptr, 0);
  gemm_bt<0><<<dim3(C_/128, M_/128), 256, 0, stream>>>(xm, kwt, C_, C_, kf, nullptr, nullptr, nullptr, nullptr, 0);
  gemm_bt<0><<<dim3(C_/128, M_/128), 256, 0, stream>>>(xm, vwt, C_, C_, vf, nullptr, nullptr, nullptr, nullptr, 0);

  // 5. RMSNorm q,k -> swizzled bf16 ; transpose v -> swizzled bf16
  rms_swz<<<dim3(M_), 256, 0, stream>>>(qf, qn_w, qbb);
  rms_swz<<<dim3(M_), 256, 0, stream>>>(kf, kn_w, kbb);
  v_transpose<<<dim3(L_/32, D_/32, B_*H_), 256, 0, stream>>>(vf, vtt);

  // 6. causal flash attention (1 q-tile/wave, descending)
  attn<<<dim3(L_/16/4, B_*H_), 256, 0, stream>>>(qbb, kbb, vtt, attn_o);

  // 7. proj + residual + gate: txt2 = txt + g1*(attn@proj)
  gemm_bt<2><<<dim3(C_/128, M_/128), 256, 0, stream>>>(attn_o, pwt, C_, C_, txt2, nullptr, nullptr, txt, mod, 2*C_);

  // 8. LN2 + modulate
  ln_mod<<<dim3(M_), 256, 0, stream>>>(txt2, mod, x2m, 3*C_, 4*C_);

  // 9. fc1 + bias + gelu -> bf16
  gemm_bt<1><<<dim3(CM_/128, M_/128), 256, 0, stream>>>(x2m, f1wt, CM_, C_, nullptr, h1, fc1_b, nullptr, nullptr, 0);

  // 10. fc2 + bias, residual + gate -> d_out (f32)
  gemm_bt<3><<<dim3(C_/128, M_/128), 256, 0, stream>>>(h1, f2wt, C_, CM_, out, nullptr, fc2_b, txt2, mod, 5*C_);
}